// Round 5
// baseline (602.662 us; speedup 1.0000x reference)
//
#include <hip/hip_runtime.h>
#include <cstdint>
#include <cstddef>

// ---- problem constants ----
#define B_      2
#define S_      2048
#define DIM_    2048
#define H_      16
#define KV_LORA_ 512
#define NOPE_D_ 128
#define ROPE_D_ 64
#define V_D_    128
#define Q_D_    192          // NOPE_D + ROPE_D
#define EPS_    1e-6f
#define BS_     (B_ * S_)    // 4096 rows
#define CKV_P_  640          // ckv row pitch (576 padded to 5*128)

typedef __attribute__((ext_vector_type(8))) short bf16x8;
typedef __attribute__((ext_vector_type(4))) float f32x4;

__device__ __forceinline__ ushort f2bf(float f) {
    union { float f; uint32_t u; } v; v.f = f;
    uint32_t u = v.u + 0x7fff + ((v.u >> 16) & 1);  // RNE
    return (ushort)(u >> 16);
}
__device__ __forceinline__ float bf2f(ushort u) {
    union { uint32_t u; float f; } v; v.u = (uint32_t)u << 16; return v.f;
}
__device__ __forceinline__ void gll16(const void* g, void* l) {
    __builtin_amdgcn_global_load_lds(
        (const __attribute__((address_space(1))) unsigned int*)g,
        (__attribute__((address_space(3))) unsigned int*)l, 16, 0, 0);
}

// ============================================================================
// bf16 MFMA GEMM: C = A @ W^T.  (unchanged)
// ============================================================================
template <int OUT_BF16>
__global__ __launch_bounds__(256) void gemm_bf16_t(
    const ushort* __restrict__ A, const ushort* __restrict__ Bw,
    void* __restrict__ Cv, int N, int K)
{
    constexpr int BK = 64;
    __shared__ __align__(16) ushort Af[8192];
    __shared__ __align__(16) ushort Bf[8192];
    const int tid = threadIdx.x;
    const int lane = tid & 63;
    const int w = tid >> 6;
    const int l15 = lane & 15, quad = lane >> 4;
    const int m0 = blockIdx.y * 128;
    const int n0 = blockIdx.x * 128;
    const int wm0 = (w & 1) * 64, wn0 = (w >> 1) * 64;

    f32x4 acc[4][4];
#pragma unroll
    for (int i = 0; i < 4; ++i)
#pragma unroll
        for (int j = 0; j < 4; ++j) acc[i][j] = (f32x4){0.f, 0.f, 0.f, 0.f};

    const ushort* ap[4]; const ushort* bp[4];
    ushort* al[4]; ushort* bl[4];
#pragma unroll
    for (int t = 0; t < 4; ++t) {
        int ia = w * 4 + t;
        int kk = ia >> 3, q = (ia >> 1) & 3, mh = ia & 1;
        int koff = kk * 32 + q * 8;
        ap[t] = A  + (size_t)(m0 + mh * 64 + lane) * K + koff;
        bp[t] = Bw + (size_t)(n0 + mh * 64 + lane) * K + koff;
        al[t] = &Af[ia * 512];
        bl[t] = &Bf[ia * 512];
    }

    for (int k0 = 0; k0 < K; k0 += BK) {
        __syncthreads();
#pragma unroll
        for (int t = 0; t < 4; ++t) {
            gll16(ap[t], al[t]);
            gll16(bp[t], bl[t]);
            ap[t] += BK; bp[t] += BK;
        }
        __syncthreads();

        bf16x8 a0[4], a1[4], b0[4], b1[4];
#pragma unroll
        for (int i = 0; i < 4; ++i) {
            a0[i] = *(const bf16x8*)&Af[((0 + quad) * 128 + wm0 + i * 16 + l15) * 8];
            a1[i] = *(const bf16x8*)&Af[((4 + quad) * 128 + wm0 + i * 16 + l15) * 8];
            b0[i] = *(const bf16x8*)&Bf[((0 + quad) * 128 + wn0 + i * 16 + l15) * 8];
            b1[i] = *(const bf16x8*)&Bf[((4 + quad) * 128 + wn0 + i * 16 + l15) * 8];
        }
#pragma unroll
        for (int i = 0; i < 4; ++i)
#pragma unroll
            for (int j = 0; j < 4; ++j)
                acc[i][j] = __builtin_amdgcn_mfma_f32_16x16x32_bf16(a0[i], b0[j], acc[i][j], 0, 0, 0);
#pragma unroll
        for (int i = 0; i < 4; ++i)
#pragma unroll
            for (int j = 0; j < 4; ++j)
                acc[i][j] = __builtin_amdgcn_mfma_f32_16x16x32_bf16(a1[i], b1[j], acc[i][j], 0, 0, 0);
    }

#pragma unroll
    for (int i = 0; i < 4; ++i)
#pragma unroll
        for (int r = 0; r < 4; ++r) {
            size_t base = (size_t)(m0 + wm0 + i * 16 + quad * 4 + r) * N + n0 + wn0 + l15;
#pragma unroll
            for (int j = 0; j < 4; ++j) {
                float v = acc[i][j][r];
                if (OUT_BF16) ((ushort*)Cv)[base + j * 16] = f2bf(v);
                else          ((float*)Cv)[base + j * 16] = v;
            }
        }
}

// ============================================================================
// fp32 -> bf16 cast, 8 elems/thread
// ============================================================================
__global__ __launch_bounds__(256) void cast8(
    const float* __restrict__ s, ushort* __restrict__ d)
{
    size_t i = ((size_t)blockIdx.x * 256 + threadIdx.x) * 8;
    float4 a = *(const float4*)(s + i);
    float4 b = *(const float4*)(s + i + 4);
    ushort4 o0, o1;
    o0.x = f2bf(a.x); o0.y = f2bf(a.y); o0.z = f2bf(a.z); o0.w = f2bf(a.w);
    o1.x = f2bf(b.x); o1.y = f2bf(b.y); o1.z = f2bf(b.z); o1.w = f2bf(b.w);
    *(ushort4*)(d + i) = o0;
    *(ushort4*)(d + i + 4) = o1;
}

// wkva (576 x 2048) -> bf16 (640 x 2048), rows 576..639 zeroed
__global__ __launch_bounds__(256) void cast_wkva_pad(
    const float* __restrict__ s, ushort* __restrict__ d)
{
    size_t i = ((size_t)blockIdx.x * 256 + threadIdx.x) * 8;
    size_t row = i >> 11;
    ushort4 o0 = {0,0,0,0}, o1 = {0,0,0,0};
    if (row < 576) {
        float4 a = *(const float4*)(s + i);
        float4 b = *(const float4*)(s + i + 4);
        o0.x = f2bf(a.x); o0.y = f2bf(a.y); o0.z = f2bf(a.z); o0.w = f2bf(a.w);
        o1.x = f2bf(b.x); o1.y = f2bf(b.y); o1.z = f2bf(b.z); o1.w = f2bf(b.w);
    }
    *(ushort4*)(d + i) = o0;
    *(ushort4*)(d + i + 4) = o1;
}

// ============================================================================
// RMSNorm over ckv[:, :512] (fp32, pitch 640) -> cnorm bf16
// ============================================================================
__global__ __launch_bounds__(256) void rmsnorm_k(
    const float* __restrict__ ckv, const float* __restrict__ nw,
    ushort* __restrict__ cnorm)
{
    const int lane = threadIdx.x & 63;
    const int row = blockIdx.x * 4 + (threadIdx.x >> 6);
    const float* src = ckv + (size_t)row * CKV_P_;
    float4 a = *(const float4*)(src + lane * 4);
    float4 b = *(const float4*)(src + 256 + lane * 4);
    float ss = a.x*a.x + a.y*a.y + a.z*a.z + a.w*a.w
             + b.x*b.x + b.y*b.y + b.z*b.z + b.w*b.w;
#pragma unroll
    for (int off = 32; off > 0; off >>= 1) ss += __shfl_xor(ss, off, 64);
    float rs = rsqrtf(ss * (1.0f / 512.0f) + EPS_);
    float4 w0 = *(const float4*)(nw + lane * 4);
    float4 w1 = *(const float4*)(nw + 256 + lane * 4);
    ushort* dst = cnorm + (size_t)row * KV_LORA_;
    ushort4 o0, o1;
    o0.x = f2bf(a.x*rs*w0.x); o0.y = f2bf(a.y*rs*w0.y);
    o0.z = f2bf(a.z*rs*w0.z); o0.w = f2bf(a.w*rs*w0.w);
    o1.x = f2bf(b.x*rs*w1.x); o1.y = f2bf(b.y*rs*w1.y);
    o1.z = f2bf(b.z*rs*w1.z); o1.w = f2bf(b.w*rs*w1.w);
    *(ushort4*)(dst + lane * 4) = o0;
    *(ushort4*)(dst + 256 + lane * 4) = o1;
}

// ============================================================================
// RoPE k_rope from ckv fp32 (pitch 640, cols 512..575) -> krb bf16
// ============================================================================
__global__ __launch_bounds__(256) void rope_cast_k(
    const float* __restrict__ ckv, const float* __restrict__ rope_cache,
    ushort* __restrict__ krb)
{
    const int lane = threadIdx.x & 63;
    const int w = blockIdx.x * 4 + (threadIdx.x >> 6);
    const int s = w & (S_ - 1);
    float v = ckv[(size_t)w * CKV_P_ + KV_LORA_ + lane];
    float other = __shfl_xor(v, 32, 64);
    float rot = (lane < 32) ? -other : other;
    float c  = rope_cache[s * (2 * ROPE_D_) + lane];
    float sn = rope_cache[s * (2 * ROPE_D_) + ROPE_D_ + lane];
    krb[(size_t)w * ROPE_D_ + lane] = f2bf(v * c + rot * sn);
}

// ============================================================================
// V transpose: kvb bf16 [bs][h*256 + 128 + c] -> vT [b*16+h][vd][s]
// ============================================================================
__global__ __launch_bounds__(256) void transpose_v(
    const ushort* __restrict__ kvb, ushort* __restrict__ vT)
{
    __shared__ ushort T[128][80];
    const int tid = threadIdx.x;
    const int bh = blockIdx.y;
    const int b = bh >> 4, h = bh & 15;
    const int sb = blockIdx.x * 64;
    const size_t rowbase = (size_t)b * S_ + sb;
#pragma unroll
    for (int it = 0; it < 4; ++it) {
        int f = tid + 256 * it;
        int r = f >> 4, c8 = (f & 15) * 8;
        bf16x8 v = *(const bf16x8*)(kvb + (rowbase + r) * 4096 + h * 256 + 128 + c8);
#pragma unroll
        for (int e = 0; e < 8; ++e) T[c8 + e][r] = (ushort)v[e];
    }
    __syncthreads();
#pragma unroll
    for (int it = 0; it < 4; ++it) {
        int f = tid + 256 * it;
        int vd = f >> 3, s8 = (f & 7) * 8;
        *(bf16x8*)(vT + ((size_t)bh * 128 + vd) * S_ + sb + s8) =
            *(const bf16x8*)&T[vd][s8];
    }
}

// ============================================================================
// MFMA flash attention v3.
//  - q-tile = 128 rows/block; wave w owns strips {w*16, 64+w*16} (16 rows ea).
//  - Pairing: block p does q-tiles p and 15-p => exactly 34 K-iters/block.
//  - RoPE fused into Q A-frag load (pairs (128+t,160+t) are lane-local across
//    qf[4]/qf[5]); softmax scale folded into Q before bf16 encode.
//  - Strips processed sequentially so Pf is 64 rows (8 KB); waves touch only
//    their own 16 Pf rows => no extra barriers.  LDS 48 KB -> 3 blocks/CU.
//  - Ballot-gated alpha-rescale skip (exact: alpha==1 iff mx==mprev).
//  - Row-sum of P via ones-frag MFMA into lsum accumulator.
// ============================================================================
__global__ __launch_bounds__(256) void mla_attn_mfma3(
    const ushort* __restrict__ q_bf, const ushort* __restrict__ kvb,
    const ushort* __restrict__ krb, const ushort* __restrict__ vT,
    const float* __restrict__ rope_cache, ushort* __restrict__ attn)
{
    __shared__ __align__(16) ushort Kf[24 * 64 * 8];   // 24 KB
    __shared__ __align__(16) ushort Vf[8 * 128 * 8];   // 16 KB
    __shared__ __align__(16) ushort Pf[8 * 64 * 8];    //  8 KB

    const int tid = threadIdx.x;
    const int lane = tid & 63;
    const int w = tid >> 6;
    const int bh = blockIdx.y;
    const int b = bh >> 4, h = bh & 15;
    const size_t bS = (size_t)b * S_;
    const int l15 = lane & 15, quad = lane >> 4;
    const int w16 = w * 16;
    const float scale = 0.07216878364870323f;  // 192^-0.5

    bf16x8 ones_frag = {};
    if (l15 == 0) {
#pragma unroll
        for (int e = 0; e < 8; ++e) ones_frag[e] = (short)0x3F80;  // bf16 1.0
    }

#pragma unroll 1
    for (int hv = 0; hv < 2; ++hv) {
        const int qt = hv == 0 ? (int)blockIdx.x : 15 - (int)blockIdx.x;
        const int qbase = qt * 128;
        const int nkt = 2 * qt + 2;

        // ---- load Q A-frags: fused rope + scale ----
        bf16x8 qf[12];
#pragma unroll
        for (int ss = 0; ss < 2; ++ss) {
            const int r0 = qbase + ss * 64 + w16;
            const int s = r0 + l15;
            const ushort* qrow = q_bf + (bS + r0 + l15) * (H_ * Q_D_) + h * Q_D_;
#pragma unroll
            for (int ks = 0; ks < 4; ++ks) {
                bf16x8 a = *(const bf16x8*)(qrow + ks * 32 + quad * 8);
                bf16x8 o;
#pragma unroll
                for (int e = 0; e < 8; ++e)
                    o[e] = (short)f2bf(bf2f((ushort)a[e]) * scale);
                qf[ss * 6 + ks] = o;
            }
            {
                bf16x8 a4 = *(const bf16x8*)(qrow + 128 + quad * 8);
                bf16x8 a5 = *(const bf16x8*)(qrow + 160 + quad * 8);
                const float* rc = rope_cache + (size_t)s * (2 * ROPE_D_) + quad * 8;
                float4 c0 = *(const float4*)(rc);
                float4 c1 = *(const float4*)(rc + 4);
                float4 s0 = *(const float4*)(rc + ROPE_D_);
                float4 s1 = *(const float4*)(rc + ROPE_D_ + 4);
                float cc[8] = {c0.x, c0.y, c0.z, c0.w, c1.x, c1.y, c1.z, c1.w};
                float sn[8] = {s0.x, s0.y, s0.z, s0.w, s1.x, s1.y, s1.z, s1.w};
                bf16x8 o4, o5;
#pragma unroll
                for (int e = 0; e < 8; ++e) {
                    float v4 = bf2f((ushort)a4[e]), v5 = bf2f((ushort)a5[e]);
                    o4[e] = (short)f2bf((v4 * cc[e] - v5 * sn[e]) * scale);
                    o5[e] = (short)f2bf((v5 * cc[e] + v4 * sn[e]) * scale);
                }
                qf[ss * 6 + 4] = o4;
                qf[ss * 6 + 5] = o5;
            }
        }

        f32x4 ov[16];
#pragma unroll
        for (int i = 0; i < 16; ++i) ov[i] = (f32x4){0.f, 0.f, 0.f, 0.f};
        f32x4 lsum[2];
        lsum[0] = (f32x4){0.f, 0.f, 0.f, 0.f};
        lsum[1] = (f32x4){0.f, 0.f, 0.f, 0.f};
        float m_run[8];
#pragma unroll
        for (int i = 0; i < 8; ++i) m_run[i] = -3e38f;

        for (int kt = 0; kt < nkt; ++kt) {
            const int kbase = kt * 64;
            __syncthreads();   // WAR: prior iter's Kf/Vf reads done
            // ---- stage K tile ----
#pragma unroll
            for (int ks = 0; ks < 6; ++ks) {
                ushort* dst = &Kf[(size_t)((ks * 4 + w) * 64) * 8];
                const ushort* src = (ks < 4)
                    ? kvb + (bS + kbase + lane) * 4096 + h * 256 + ks * 32 + w * 8
                    : krb + (bS + kbase + lane) * 64 + (ks - 4) * 32 + w * 8;
                gll16(src, dst);
            }
            // ---- stage V tile ----
#pragma unroll
            for (int t = 0; t < 4; ++t) {
                int ks2 = t >> 1, hh = t & 1;
                ushort* dst = &Vf[(size_t)((ks2 * 4 + w) * 128 + hh * 64) * 8];
                const ushort* src =
                    vT + ((size_t)bh * 128 + hh * 64 + lane) * S_ + kbase + ks2 * 32 + w * 8;
                gll16(src, dst);
            }
            __syncthreads();   // staging visible

#pragma unroll
            for (int ss = 0; ss < 2; ++ss) {
                const int r0 = qbase + ss * 64 + w16;
                if (kbase > r0 + 15) continue;   // strip fully masked

                // ---- QK^T: 16x64 ----
                f32x4 sc[4];
#pragma unroll
                for (int nt = 0; nt < 4; ++nt) sc[nt] = (f32x4){0.f, 0.f, 0.f, 0.f};
#pragma unroll
                for (int ks = 0; ks < 6; ++ks) {
                    bf16x8 a = qf[ss * 6 + ks];
#pragma unroll
                    for (int nt = 0; nt < 4; ++nt) {
                        bf16x8 bb = *(const bf16x8*)&Kf[(size_t)((ks * 4 + quad) * 64 + nt * 16 + l15) * 8];
                        sc[nt] = __builtin_amdgcn_mfma_f32_16x16x32_bf16(a, bb, sc[nt], 0, 0, 0);
                    }
                }

                // ---- mask (wave-uniform path split) + row max ----
                float mxs[4];
                bool anych = false;
                if (kbase + 63 > r0) {
#pragma unroll
                    for (int i = 0; i < 4; ++i) {
                        int qrow = r0 + quad * 4 + i;
                        float mx = m_run[ss * 4 + i];
#pragma unroll
                        for (int nt = 0; nt < 4; ++nt) {
                            float v = sc[nt][i];
                            if ((kbase + nt * 16 + l15) > qrow) v = -3e38f;
                            sc[nt][i] = v;
                            mx = fmaxf(mx, v);
                        }
#pragma unroll
                        for (int m = 1; m < 16; m <<= 1) mx = fmaxf(mx, __shfl_xor(mx, m, 64));
                        anych |= (mx > m_run[ss * 4 + i]);
                        mxs[i] = mx;
                    }
                } else {
#pragma unroll
                    for (int i = 0; i < 4; ++i) {
                        float mx = m_run[ss * 4 + i];
#pragma unroll
                        for (int nt = 0; nt < 4; ++nt) mx = fmaxf(mx, sc[nt][i]);
#pragma unroll
                        for (int m = 1; m < 16; m <<= 1) mx = fmaxf(mx, __shfl_xor(mx, m, 64));
                        anych |= (mx > m_run[ss * 4 + i]);
                        mxs[i] = mx;
                    }
                }

                // ---- ballot-gated rescale (exact skip: alpha==1) ----
                if (__ballot(anych)) {
#pragma unroll
                    for (int i = 0; i < 4; ++i) {
                        float alpha = __expf(m_run[ss * 4 + i] - mxs[i]);
                        lsum[ss][i] *= alpha;
#pragma unroll
                        for (int nt2 = 0; nt2 < 8; ++nt2) ov[ss * 8 + nt2][i] *= alpha;
                    }
                }
#pragma unroll
                for (int i = 0; i < 4; ++i) m_run[ss * 4 + i] = mxs[i];

                // ---- P = exp(sc - mx) -> fragment-order Pf (own rows) ----
#pragma unroll
                for (int nt = 0; nt < 4; ++nt) {
                    int c = nt * 16 + l15;
                    size_t pb = (size_t)(((c >> 5) * 4 + ((c >> 3) & 3)) * 64) * 8 + (c & 7);
#pragma unroll
                    for (int i = 0; i < 4; ++i)
                        Pf[pb + (size_t)(w16 + quad * 4 + i) * 8] = f2bf(__expf(sc[nt][i] - mxs[i]));
                }

                // ---- PV (+ row-sum via ones-frag) ----
#pragma unroll
                for (int ks2p = 0; ks2p < 2; ++ks2p) {
                    bf16x8 pa = *(const bf16x8*)&Pf[(size_t)((ks2p * 4 + quad) * 64 + w16 + l15) * 8];
                    lsum[ss] = __builtin_amdgcn_mfma_f32_16x16x32_bf16(pa, ones_frag, lsum[ss], 0, 0, 0);
#pragma unroll
                    for (int nt2 = 0; nt2 < 8; ++nt2) {
                        bf16x8 vb = *(const bf16x8*)&Vf[(size_t)((ks2p * 4 + quad) * 128 + nt2 * 16 + l15) * 8];
                        ov[ss * 8 + nt2] = __builtin_amdgcn_mfma_f32_16x16x32_bf16(pa, vb, ov[ss * 8 + nt2], 0, 0, 0);
                    }
                }
            }
        }

        // ---- epilogue ----
#pragma unroll
        for (int ss = 0; ss < 2; ++ss)
#pragma unroll
            for (int i = 0; i < 4; ++i) {
                float l = __shfl(lsum[ss][i], lane & 48, 64);
                float inv = 1.0f / l;
                size_t base = (bS + qbase + ss * 64 + w16 + quad * 4 + i) * (size_t)(H_ * V_D_) + h * V_D_;
#pragma unroll
                for (int nt2 = 0; nt2 < 8; ++nt2)
                    attn[base + nt2 * 16 + l15] = f2bf(ov[ss * 8 + nt2][i] * inv);
            }
    }
}

// ============================================================================
// launch
// ============================================================================
extern "C" void kernel_launch(void* const* d_in, const int* in_sizes, int n_in,
                              void* d_out, int out_size, void* d_ws, size_t ws_size,
                              hipStream_t stream)
{
    const float* x          = (const float*)d_in[0];
    const float* rope_cache = (const float*)d_in[1];
    const float* wq         = (const float*)d_in[2];
    const float* wkva       = (const float*)d_in[3];
    const float* norm_w     = (const float*)d_in[4];
    const float* wkvb       = (const float*)d_in[5];
    const float* wo         = (const float*)d_in[6];
    float* out = (float*)d_out;

    char* p = (char*)d_ws;
    ushort* xb       = (ushort*)p; p += (size_t)BS_ * DIM_ * 2;
    ushort* q_bf     = (ushort*)p; p += (size_t)BS_ * H_ * Q_D_ * 2;
    float*  ckv      = (float*) p; p += (size_t)BS_ * CKV_P_ * 4;
    ushort* cnorm_bf = (ushort*)p; p += (size_t)BS_ * KV_LORA_ * 2;
    ushort* kvb      = (ushort*)p; p += (size_t)BS_ * 4096 * 2;
    ushort* krb      = (ushort*)p; p += (size_t)BS_ * ROPE_D_ * 2;
    ushort* vT       = (ushort*)p; p += (size_t)32 * 128 * S_ * 2;
    ushort* attn_bf  = (ushort*)p; p += (size_t)BS_ * 2048 * 2;
    ushort* wq_bf    = (ushort*)p; p += (size_t)3072 * DIM_ * 2;
    ushort* wkva_bf  = (ushort*)p; p += (size_t)CKV_P_ * DIM_ * 2;
    ushort* wkvb_bf  = (ushort*)p; p += (size_t)4096 * KV_LORA_ * 2;
    ushort* wo_bf    = (ushort*)p; p += (size_t)DIM_ * 2048 * 2;

    dim3 blk(256);

    cast8<<<(BS_ * DIM_) / (8 * 256), blk, 0, stream>>>(x, xb);
    cast8<<<(3072 * DIM_) / (8 * 256), blk, 0, stream>>>(wq, wq_bf);
    cast_wkva_pad<<<(CKV_P_ * DIM_) / (8 * 256), blk, 0, stream>>>(wkva, wkva_bf);
    cast8<<<(4096 * KV_LORA_) / (8 * 256), blk, 0, stream>>>(wkvb, wkvb_bf);
    cast8<<<(DIM_ * 2048) / (8 * 256), blk, 0, stream>>>(wo, wo_bf);

    // 1. q_bf = x @ wq^T          (4096 x 3072 x 2048)
    gemm_bf16_t<1><<<dim3(3072 / 128, BS_ / 128), blk, 0, stream>>>(
        xb, wq_bf, q_bf, 3072, DIM_);
    // 2. ckv = x @ wkva^T         (4096 x 640 x 2048), fp32 out
    gemm_bf16_t<0><<<dim3(CKV_P_ / 128, BS_ / 128), blk, 0, stream>>>(
        xb, wkva_bf, ckv, CKV_P_, DIM_);
    // 3. cnorm_bf = rmsnorm(ckv[:, :512]) * norm_w
    rmsnorm_k<<<BS_ / 4, blk, 0, stream>>>(ckv, norm_w, cnorm_bf);
    // 4. krb = rope(ckv[:, 512:576])
    rope_cast_k<<<BS_ / 4, blk, 0, stream>>>(ckv, rope_cache, krb);
    // 5. kvb = cnorm @ wkvb^T     (4096 x 4096 x 512), bf16 out
    gemm_bf16_t<1><<<dim3(4096 / 128, BS_ / 128), blk, 0, stream>>>(
        cnorm_bf, wkvb_bf, kvb, 4096, KV_LORA_);
    // 6. vT = transpose(V part of kvb)
    transpose_v<<<dim3(S_ / 64, B_ * H_), blk, 0, stream>>>(kvb, vT);
    // 7. flash attention v3 (rope fused) -> attn_bf
    mla_attn_mfma3<<<dim3(8, B_ * H_), blk, 0, stream>>>(
        q_bf, kvb, krb, vT, rope_cache, attn_bf);
    // 8. out = attn @ wo^T        (4096 x 2048 x 2048), fp32 out
    gemm_bf16_t<0><<<dim3(DIM_ / 128, BS_ / 128), blk, 0, stream>>>(
        attn_bf, wo_bf, out, DIM_, 2048);
}